// Round 1
// baseline (46.800 us; speedup 1.0000x reference)
//
#include <hip/hip_runtime.h>
#include <math.h>

// RBF layer: out[b,u] = exp(-gamma * ||x_b - c_u||^2)
// B=8192, UNITS=2048, DIM=32, all float32.
//
// Strategy: expand ||x-c||^2 = ||x||^2 + ||c||^2 - 2 x.c  (1 FMA/dim instead
// of sub+fma). Safe because min distance^2 ~ 8.4 => outputs <= 2.3e-4, so
// absolute error in the exponent is multiplied by a tiny exp(-d).
//
// Thread owns one unit (center in 32 VGPRs). Block tile: 64 rows x 256 units.
// x-row elements are wave-uniform -> scalar loads (no VALU cost).

#define BATCH   8192
#define UNITS   2048
#define DIM     32
#define ROWS_PB 64
#define THREADS 256

__global__ __launch_bounds__(THREADS) void rbf_kernel(
    const float* __restrict__ x,
    const float* __restrict__ centers,
    const float* __restrict__ gamma,
    float* __restrict__ out)
{
    __shared__ float s_xn[ROWS_PB];

    const int tid = threadIdx.x;
    const int u   = blockIdx.x * THREADS + tid;       // unit this thread owns
    const int r0  = blockIdx.y * ROWS_PB;             // first row of tile

    // ---- load this thread's center into registers, compute ||c||^2 ----
    float c[DIM];
    const float4* cv = reinterpret_cast<const float4*>(centers + (size_t)u * DIM);
#pragma unroll
    for (int i = 0; i < DIM / 4; ++i) {
        float4 t = cv[i];
        c[4*i+0] = t.x; c[4*i+1] = t.y; c[4*i+2] = t.z; c[4*i+3] = t.w;
    }
    float cn = 0.f;
#pragma unroll
    for (int d = 0; d < DIM; ++d) cn = fmaf(c[d], c[d], cn);

    // ---- prologue: per-row ||x_r||^2 into LDS (one thread per row) ----
    if (tid < ROWS_PB) {
        const float4* xv = reinterpret_cast<const float4*>(x + (size_t)(r0 + tid) * DIM);
        float s = 0.f;
#pragma unroll
        for (int i = 0; i < DIM / 4; ++i) {
            float4 t = xv[i];
            s = fmaf(t.x, t.x, s);
            s = fmaf(t.y, t.y, s);
            s = fmaf(t.z, t.z, s);
            s = fmaf(t.w, t.w, s);
        }
        s_xn[tid] = s;
    }
    __syncthreads();

    // exp(-g*v) == exp2(kg * v),  kg = -g * log2(e)
    const float kg = -gamma[0] * 1.4426950408889634f;

    // ---- main loop: 4 rows at a time, 32 FMAs per output ----
    for (int rr = 0; rr < ROWS_PB; rr += 4) {
        const float* xr = x + (size_t)(r0 + rr) * DIM;   // uniform address -> s_load
        float a0 = 0.f, a1 = 0.f, a2 = 0.f, a3 = 0.f;
#pragma unroll
        for (int d = 0; d < DIM; ++d) {
            const float cd = c[d];
            a0 = fmaf(xr[d],           cd, a0);
            a1 = fmaf(xr[DIM + d],     cd, a1);
            a2 = fmaf(xr[2 * DIM + d], cd, a2);
            a3 = fmaf(xr[3 * DIM + d], cd, a3);
        }
        const float t0 = s_xn[rr + 0] + cn;
        const float t1 = s_xn[rr + 1] + cn;
        const float t2 = s_xn[rr + 2] + cn;
        const float t3 = s_xn[rr + 3] + cn;

        const float o0 = exp2f(kg * fmaf(-2.f, a0, t0));
        const float o1 = exp2f(kg * fmaf(-2.f, a1, t1));
        const float o2 = exp2f(kg * fmaf(-2.f, a2, t2));
        const float o3 = exp2f(kg * fmaf(-2.f, a3, t3));

        float* orow = out + (size_t)(r0 + rr) * UNITS + u;
        orow[0]         = o0;
        orow[UNITS]     = o1;
        orow[2 * UNITS] = o2;
        orow[3 * UNITS] = o3;
    }
}

extern "C" void kernel_launch(void* const* d_in, const int* in_sizes, int n_in,
                              void* d_out, int out_size, void* d_ws, size_t ws_size,
                              hipStream_t stream)
{
    const float* x       = (const float*)d_in[0];
    const float* centers = (const float*)d_in[1];
    const float* gamma   = (const float*)d_in[2];
    float* out           = (float*)d_out;

    dim3 grid(UNITS / THREADS, BATCH / ROWS_PB);   // (8, 128) = 1024 blocks
    dim3 block(THREADS);
    rbf_kernel<<<grid, block, 0, stream>>>(x, centers, gamma, out);
}

// Round 2
// 36.691 us; speedup vs baseline: 1.2755x; 1.2755x over previous
//
#include <hip/hip_runtime.h>
#include <math.h>

// RBF layer: out[b,u] = exp(-gamma * ||x_b - c_u||^2)
// B=8192, UNITS=2048, DIM=32, all float32.
//
// ||x-c||^2 expanded: ||x||^2 + ||c||^2 - 2 x.c  (1 FMA/dim). Numerically safe:
// min dist^2 ~ 8.4 => outputs <= 2.3e-4, exponent-error budget ~0.02 abs.
//
// R1 changes vs R0 (was latency-bound: 33% VALU, 31% occupancy):
//  - ROWS_PB 64->32: 2048 blocks = 8 blocks/CU = 32 waves/CU (full occupancy).
//    VGPR=44 fits __launch_bounds__(256,8) (<=64 VGPR for 8 waves/SIMD).
//  - fold gamma*log2(e) and the -2 into precomputed constants; LDS holds
//    kg*||x_r||^2 so the epilogue is 1 add + 1 fma + v_exp_f32.
//  - #pragma unroll 2 on the row loop for s_load pipelining scope.

#define BATCH   8192
#define UNITS   2048
#define DIM     32
#define ROWS_PB 32
#define THREADS 256

__global__ __launch_bounds__(THREADS, 8) void rbf_kernel(
    const float* __restrict__ x,
    const float* __restrict__ centers,
    const float* __restrict__ gamma,
    float* __restrict__ out)
{
    __shared__ float s_xb[ROWS_PB];   // kg * ||x_r||^2

    const int tid = threadIdx.x;
    const int u   = blockIdx.x * THREADS + tid;       // unit this thread owns
    const int r0  = blockIdx.y * ROWS_PB;             // first row of tile

    // exp(-g*v) == exp2(kg*v), kg = -g*log2(e)
    const float kg = -gamma[0] * 1.4426950408889634f;
    const float m2 = -2.0f * kg;                      // coefficient of x.c

    // ---- this thread's center -> registers; kg*||c||^2 ----
    float c[DIM];
    const float4* cv = reinterpret_cast<const float4*>(centers + (size_t)u * DIM);
#pragma unroll
    for (int i = 0; i < DIM / 4; ++i) {
        float4 t = cv[i];
        c[4*i+0] = t.x; c[4*i+1] = t.y; c[4*i+2] = t.z; c[4*i+3] = t.w;
    }
    float cn = 0.f;
#pragma unroll
    for (int d = 0; d < DIM; ++d) cn = fmaf(c[d], c[d], cn);
    const float kgcn = kg * cn;

    // ---- prologue: kg*||x_r||^2 into LDS (one thread per row) ----
    if (tid < ROWS_PB) {
        const float4* xv = reinterpret_cast<const float4*>(x + (size_t)(r0 + tid) * DIM);
        float s = 0.f;
#pragma unroll
        for (int i = 0; i < DIM / 4; ++i) {
            float4 t = xv[i];
            s = fmaf(t.x, t.x, s);
            s = fmaf(t.y, t.y, s);
            s = fmaf(t.z, t.z, s);
            s = fmaf(t.w, t.w, s);
        }
        s_xb[tid] = kg * s;
    }
    __syncthreads();

    // ---- main loop: 4 rows per iteration, 32 FMAs per output ----
#pragma unroll 2
    for (int rr = 0; rr < ROWS_PB; rr += 4) {
        const float* xr = x + (size_t)(r0 + rr) * DIM;   // wave-uniform -> s_load
        float a0 = 0.f, a1 = 0.f, a2 = 0.f, a3 = 0.f;
#pragma unroll
        for (int d = 0; d < DIM; ++d) {
            const float cd = c[d];
            a0 = fmaf(xr[d],           cd, a0);
            a1 = fmaf(xr[DIM + d],     cd, a1);
            a2 = fmaf(xr[2 * DIM + d], cd, a2);
            a3 = fmaf(xr[3 * DIM + d], cd, a3);
        }
        const float b0 = s_xb[rr + 0] + kgcn;
        const float b1 = s_xb[rr + 1] + kgcn;
        const float b2 = s_xb[rr + 2] + kgcn;
        const float b3 = s_xb[rr + 3] + kgcn;

        const float o0 = __builtin_amdgcn_exp2f(fmaf(m2, a0, b0));
        const float o1 = __builtin_amdgcn_exp2f(fmaf(m2, a1, b1));
        const float o2 = __builtin_amdgcn_exp2f(fmaf(m2, a2, b2));
        const float o3 = __builtin_amdgcn_exp2f(fmaf(m2, a3, b3));

        float* orow = out + (size_t)(r0 + rr) * UNITS + u;
        orow[0]         = o0;
        orow[UNITS]     = o1;
        orow[2 * UNITS] = o2;
        orow[3 * UNITS] = o3;
    }
}

extern "C" void kernel_launch(void* const* d_in, const int* in_sizes, int n_in,
                              void* d_out, int out_size, void* d_ws, size_t ws_size,
                              hipStream_t stream)
{
    const float* x       = (const float*)d_in[0];
    const float* centers = (const float*)d_in[1];
    const float* gamma   = (const float*)d_in[2];
    float* out           = (float*)d_out;

    dim3 grid(UNITS / THREADS, BATCH / ROWS_PB);   // (8, 256) = 2048 blocks
    dim3 block(THREADS);
    rbf_kernel<<<grid, block, 0, stream>>>(x, centers, gamma, out);
}

// Round 3
// 30.222 us; speedup vs baseline: 1.5486x; 1.2140x over previous
//
#include <hip/hip_runtime.h>
#include <math.h>

// RBF layer: out[b,u] = exp(-gamma * ||x_b - c_u||^2)
// B=8192, UNITS=2048, DIM=32, all float32.
//
// ||x-c||^2 expanded: ||x||^2 + ||c||^2 - 2 x.c. Numerically safe: min dist^2
// ~8.4 => outputs <= 2.3e-4; exponent absolute-error budget ~0.02.
//
// R2 diagnosis: all waves stalled together on the scalar-memory path
// (512 B/iter of s_load x-data, one scalar pipe per CU, SGPR-starved
// prefetch). R2 fix: x tile staged in LDS once per block; main loop reads x
// with ds_read_b128 at wave-uniform addresses -> hardware broadcast, no bank
// conflicts, VGPR-prefetchable. Row norms via 8-lane shfl_xor during staging.

#define BATCH   8192
#define UNITS   2048
#define DIM     32
#define ROWS_PB 32
#define THREADS 256

__global__ __launch_bounds__(THREADS, 6) void rbf_kernel(
    const float* __restrict__ x,
    const float* __restrict__ centers,
    const float* __restrict__ gamma,
    float* __restrict__ out)
{
    __shared__ float s_x[ROWS_PB][DIM];   // 4 KB x tile
    __shared__ float s_xb[ROWS_PB];       // kg * ||x_r||^2

    const int tid = threadIdx.x;
    const int u   = blockIdx.x * THREADS + tid;       // unit this thread owns
    const int r0  = blockIdx.y * ROWS_PB;             // first row of tile

    // exp(-g*v) == exp2(kg*v), kg = -g*log2(e)
    const float kg = -gamma[0] * 1.4426950408889634f;
    const float m2 = -2.0f * kg;                      // coefficient of x.c

    // ---- cooperative x-tile staging: thread t -> row t>>3, dims (t&7)*4.. ----
    {
        const int row = tid >> 3;
        const int grp = tid & 7;
        float4 t4 = *reinterpret_cast<const float4*>(
            x + (size_t)(r0 + row) * DIM + grp * 4);
        *reinterpret_cast<float4*>(&s_x[row][grp * 4]) = t4;

        // partial ||x_row||^2 from this thread's 4 elements
        float p = t4.x * t4.x;
        p = fmaf(t4.y, t4.y, p);
        p = fmaf(t4.z, t4.z, p);
        p = fmaf(t4.w, t4.w, p);
        // reduce across the 8 lanes that share a row (lane-xor 1,2,4)
        p += __shfl_xor(p, 1);
        p += __shfl_xor(p, 2);
        p += __shfl_xor(p, 4);
        if (grp == 0) s_xb[row] = kg * p;
    }

    // ---- this thread's center -> registers; kg*||c||^2 ----
    float c[DIM];
    const float4* cv = reinterpret_cast<const float4*>(centers + (size_t)u * DIM);
#pragma unroll
    for (int i = 0; i < DIM / 4; ++i) {
        float4 t = cv[i];
        c[4*i+0] = t.x; c[4*i+1] = t.y; c[4*i+2] = t.z; c[4*i+3] = t.w;
    }
    float cn = 0.f;
#pragma unroll
    for (int d = 0; d < DIM; ++d) cn = fmaf(c[d], c[d], cn);
    const float kgcn = kg * cn;

    __syncthreads();

    // ---- main loop: 4 rows per iteration; x via broadcast ds_read_b128 ----
#pragma unroll 2
    for (int rr = 0; rr < ROWS_PB; rr += 4) {
        float a0 = 0.f, a1 = 0.f, a2 = 0.f, a3 = 0.f;
#pragma unroll
        for (int g = 0; g < DIM / 4; ++g) {
            const float4 x0 = *reinterpret_cast<const float4*>(&s_x[rr + 0][g * 4]);
            const float4 x1 = *reinterpret_cast<const float4*>(&s_x[rr + 1][g * 4]);
            const float4 x2 = *reinterpret_cast<const float4*>(&s_x[rr + 2][g * 4]);
            const float4 x3 = *reinterpret_cast<const float4*>(&s_x[rr + 3][g * 4]);
            const float c0 = c[4*g+0], c1 = c[4*g+1], c2 = c[4*g+2], c3 = c[4*g+3];
            a0 = fmaf(x0.x, c0, a0); a0 = fmaf(x0.y, c1, a0);
            a0 = fmaf(x0.z, c2, a0); a0 = fmaf(x0.w, c3, a0);
            a1 = fmaf(x1.x, c0, a1); a1 = fmaf(x1.y, c1, a1);
            a1 = fmaf(x1.z, c2, a1); a1 = fmaf(x1.w, c3, a1);
            a2 = fmaf(x2.x, c0, a2); a2 = fmaf(x2.y, c1, a2);
            a2 = fmaf(x2.z, c2, a2); a2 = fmaf(x2.w, c3, a2);
            a3 = fmaf(x3.x, c0, a3); a3 = fmaf(x3.y, c1, a3);
            a3 = fmaf(x3.z, c2, a3); a3 = fmaf(x3.w, c3, a3);
        }
        const float b0 = s_xb[rr + 0] + kgcn;
        const float b1 = s_xb[rr + 1] + kgcn;
        const float b2 = s_xb[rr + 2] + kgcn;
        const float b3 = s_xb[rr + 3] + kgcn;

        const float o0 = __builtin_amdgcn_exp2f(fmaf(m2, a0, b0));
        const float o1 = __builtin_amdgcn_exp2f(fmaf(m2, a1, b1));
        const float o2 = __builtin_amdgcn_exp2f(fmaf(m2, a2, b2));
        const float o3 = __builtin_amdgcn_exp2f(fmaf(m2, a3, b3));

        float* orow = out + (size_t)(r0 + rr) * UNITS + u;
        orow[0]         = o0;
        orow[UNITS]     = o1;
        orow[2 * UNITS] = o2;
        orow[3 * UNITS] = o3;
    }
}

extern "C" void kernel_launch(void* const* d_in, const int* in_sizes, int n_in,
                              void* d_out, int out_size, void* d_ws, size_t ws_size,
                              hipStream_t stream)
{
    const float* x       = (const float*)d_in[0];
    const float* centers = (const float*)d_in[1];
    const float* gamma   = (const float*)d_in[2];
    float* out           = (float*)d_out;

    dim3 grid(UNITS / THREADS, BATCH / ROWS_PB);   // (8, 256) = 2048 blocks
    dim3 block(THREADS);
    rbf_kernel<<<grid, block, 0, stream>>>(x, centers, gamma, out);
}

// Round 4
// 28.275 us; speedup vs baseline: 1.6552x; 1.0689x over previous
//
#include <hip/hip_runtime.h>
#include <math.h>

// RBF layer: out[b,u] = exp(-gamma*||x_b - c_u||^2), B=8192, U=2048, DIM=32, f32.
//
// R3 diagnosis: LDS-return-path bound (~8192 broadcast ds_read_b128 per CU
// @ ~12cyc ~= 30-40us). Fix: MFMA. out = exp2(kg*xn + kg*cn + m2*(x.c)),
// x.c via bf16 hi/lo split (3 passes of mfma_f32_16x16x32_bf16, K=32=DIM).
// Norms computed in full f32 (they carry the magnitude); only the small
// cross-term goes through bf16. Dropped lo*lo term <= ~2e-4 in the exponent,
// output error ~1e-7 << 4.56e-6 threshold.
//
// Block = 4 waves (2x2), block tile M64 x N128; wave tile M32 x N64
// (2x4 MFMA tiles of 16x16, 3 MFMAs each). Fragments loaded directly from
// global (x 1MB + c 256KB are L1/L2-resident; no LDS staging).
// A/B frag layout: lane l -> row/col = l&15, k = (l>>4)*8 + j (contiguous 8).
// C/D layout (m89-verified): col = lane&15, row = (lane>>4)*4 + reg.

#define BATCH   8192
#define UNITS   2048
#define DIM     32
#define BM      64
#define BN      128
#define THREADS 256

typedef __attribute__((ext_vector_type(8))) short s16x8;   // 8 bf16
typedef __attribute__((ext_vector_type(4))) float f32x4;

static __device__ __forceinline__ unsigned bf16_rne(float v) {
    unsigned u = __builtin_bit_cast(unsigned, v);
    return (u + 0x7FFFu + ((u >> 16) & 1u)) >> 16;   // round-to-nearest-even
}

// Load 8 consecutive f32 and split each into bf16 hi + bf16 lo.
static __device__ __forceinline__ void load_split(const float* __restrict__ p,
                                                  s16x8& hi, s16x8& lo) {
    float4 a = *reinterpret_cast<const float4*>(p);
    float4 b = *reinterpret_cast<const float4*>(p + 4);
    float v[8] = {a.x, a.y, a.z, a.w, b.x, b.y, b.z, b.w};
#pragma unroll
    for (int j = 0; j < 8; ++j) {
        unsigned h = bf16_rne(v[j]);
        float hf = __builtin_bit_cast(float, h << 16);
        unsigned l = bf16_rne(v[j] - hf);
        hi[j] = (short)h;
        lo[j] = (short)l;
    }
}

__global__ __launch_bounds__(THREADS) void rbf_mfma(
    const float* __restrict__ x,
    const float* __restrict__ centers,
    const float* __restrict__ gamma,
    float* __restrict__ out)
{
    __shared__ __align__(16) float s_xn[BM];   // kg * ||x_row||^2
    __shared__ __align__(16) float s_cn[BN];   // kg * ||c_col||^2

    const int tid = threadIdx.x;
    const int r0  = blockIdx.y * BM;
    const int c0  = blockIdx.x * BN;

    const float kg = -gamma[0] * 1.4426950408889634f;  // -g*log2(e)
    const float m2 = -2.0f * kg;

    // ---- norms prologue (full f32) ----
    if (tid < BM) {
        const float4* p = reinterpret_cast<const float4*>(x + (size_t)(r0 + tid) * DIM);
        float s = 0.f;
#pragma unroll
        for (int i = 0; i < DIM / 4; ++i) {
            float4 t = p[i];
            s = fmaf(t.x, t.x, s); s = fmaf(t.y, t.y, s);
            s = fmaf(t.z, t.z, s); s = fmaf(t.w, t.w, s);
        }
        s_xn[tid] = kg * s;
    } else if (tid < BM + BN) {
        const int cc = tid - BM;
        const float4* p = reinterpret_cast<const float4*>(centers + (size_t)(c0 + cc) * DIM);
        float s = 0.f;
#pragma unroll
        for (int i = 0; i < DIM / 4; ++i) {
            float4 t = p[i];
            s = fmaf(t.x, t.x, s); s = fmaf(t.y, t.y, s);
            s = fmaf(t.z, t.z, s); s = fmaf(t.w, t.w, s);
        }
        s_cn[cc] = kg * s;
    }
    __syncthreads();

    const int wid  = tid >> 6;        // wave 0..3
    const int lane = tid & 63;
    const int wm   = wid >> 1;        // wave M index 0..1
    const int wn   = wid & 1;         // wave N index 0..1
    const int l16  = lane & 15;
    const int kq   = lane >> 4;       // 0..3: k-block (8 consecutive k each)

    // ---- A fragments: 2 M-tiles of x ----
    s16x8 a_hi[2], a_lo[2];
#pragma unroll
    for (int m = 0; m < 2; ++m) {
        const float* p = x + (size_t)(r0 + wm * 32 + m * 16 + l16) * DIM + kq * 8;
        load_split(p, a_hi[m], a_lo[m]);
    }
    // ---- B fragments: 4 N-tiles of centers (B^T form: unit rows, k contiguous) ----
    s16x8 b_hi[4], b_lo[4];
#pragma unroll
    for (int n = 0; n < 4; ++n) {
        const float* p = centers + (size_t)(c0 + wn * 64 + n * 16 + l16) * DIM + kq * 8;
        load_split(p, b_hi[n], b_lo[n]);
    }

    // ---- per-lane row norms: rows (lane>>4)*4 + {0..3} of each M-tile ----
    float xnq[2][4];
#pragma unroll
    for (int m = 0; m < 2; ++m) {
        const int base = wm * 32 + m * 16 + kq * 4;
#pragma unroll
        for (int j = 0; j < 4; ++j) xnq[m][j] = s_xn[base + j];
    }

    // ---- MFMA + epilogue ----
#pragma unroll
    for (int m = 0; m < 2; ++m) {
#pragma unroll
        for (int n = 0; n < 4; ++n) {
            f32x4 acc = {0.f, 0.f, 0.f, 0.f};
            // small terms first, hi*hi last
            acc = __builtin_amdgcn_mfma_f32_16x16x32_bf16(a_lo[m], b_hi[n], acc, 0, 0, 0);
            acc = __builtin_amdgcn_mfma_f32_16x16x32_bf16(a_hi[m], b_lo[n], acc, 0, 0, 0);
            acc = __builtin_amdgcn_mfma_f32_16x16x32_bf16(a_hi[m], b_hi[n], acc, 0, 0, 0);

            const int col   = c0 + wn * 64 + n * 16 + l16;
            const float cnv = s_cn[wn * 64 + n * 16 + l16];
            float* op = out + (size_t)(r0 + wm * 32 + m * 16 + kq * 4) * UNITS + col;
#pragma unroll
            for (int j = 0; j < 4; ++j) {
                float e = fmaf(m2, acc[j], xnq[m][j] + cnv);
                op[(size_t)j * UNITS] = __builtin_amdgcn_exp2f(e);
            }
        }
    }
}

extern "C" void kernel_launch(void* const* d_in, const int* in_sizes, int n_in,
                              void* d_out, int out_size, void* d_ws, size_t ws_size,
                              hipStream_t stream)
{
    const float* x       = (const float*)d_in[0];
    const float* centers = (const float*)d_in[1];
    const float* gamma   = (const float*)d_in[2];
    float* out           = (float*)d_out;

    dim3 grid(UNITS / BN, BATCH / BM);   // (16, 128) = 2048 blocks
    dim3 block(THREADS);
    rbf_mfma<<<grid, block, 0, stream>>>(x, centers, gamma, out);
}